// Round 15
// baseline (90.598 us; speedup 1.0000x reference)
//
#include <hip/hip_runtime.h>
#include <hip/hip_bf16.h>

// B=8, T=4096, C=32, D=64. Causal, no 1/sqrt(D) scaling.
constexpr int Bc = 8;
constexpr int Tt = 4096;
constexpr int Dd = 64;

typedef __attribute__((ext_vector_type(8))) short short8;   // 8 bf16 = 4 VGPRs
typedef __attribute__((ext_vector_type(4))) float floatx4;  // MFMA C/D frag
typedef __attribute__((ext_vector_type(4))) __fp16 half4;   // 4 f16 = 2 VGPRs
typedef __attribute__((ext_vector_type(2))) __fp16 half2v;
typedef uint4   __attribute__((may_alias)) uint4_a;
typedef short8  __attribute__((may_alias)) short8_a;
typedef ushort4 __attribute__((may_alias)) ushort4_a;
typedef float4  __attribute__((may_alias)) float4_a;
typedef half4   __attribute__((may_alias)) half4_a;

#define MFMA16(A, B, C)  __builtin_amdgcn_mfma_f32_16x16x32_bf16(A, B, C, 0, 0, 0)
#define MFMAH16(A, B, C) __builtin_amdgcn_mfma_f32_16x16x16f16(A, B, C, 0, 0, 0)
constexpr float LOG2E = 1.4426950408889634f;

// ---- fast fp32 -> bf16: round-half-up (u + 0x8000), pack 2 via v_perm ----
__device__ __forceinline__ unsigned rnd16(float x) {
    unsigned u; __builtin_memcpy(&u, &x, 4); return u + 0x8000u;
}
__device__ __forceinline__ unsigned pk_bf2(float lo, float hi) {
    return __builtin_amdgcn_perm(rnd16(hi), rnd16(lo), 0x07060302);
}
__device__ __forceinline__ ushort4 pack4(floatx4 d) {
    union { unsigned u[2]; ushort4 v; } r;
    r.u[0] = pk_bf2(d[0], d[1]);
    r.u[1] = pk_bf2(d[2], d[3]);
    return r.v;
}
__device__ __forceinline__ short8 cvt8(float4 a, float4 b) {
    union { unsigned u[4]; short8 s; } r;
    r.u[0] = pk_bf2(a.x, a.y);
    r.u[1] = pk_bf2(a.z, a.w);
    r.u[2] = pk_bf2(b.x, b.y);
    r.u[3] = pk_bf2(b.z, b.w);
    return r.s;
}

// ---------------------------------------------------------------------------
// Associativity-refactored fused attention (R9 algebra) with a SINGLE shared
// k-loop for the balanced q-tile pair (R14/R15):
//   Block pr owns q-tiles A = 63-pr and B = pr. B's k-range [0..pr] is a
//   subset of A's [0..63-pr] (pr <= 31), so ONE k-loop serves both: the
//   staged x-slab, the S^T A-frag reads (4 b128) and the Z^T xa reads
//   (8 b64) are SHARED between both q-tiles -> LDS instrs per unit work
//   drop ~35%, barriers/staging nearly halve vs the two-phase R13.
//   G = (log2e Wq)Wk^T [32x32] once; Y = x·G for both tiles upfront;
//   S^T = x_k·Y^T (K=32 bf16); P feeds PV directly from registers via
//   mfma_16x16x16_f16 (B-operand layout == C/D layout); Z^T += x^T·P^T;
//   O^T = Wv^T·Z^T after the additive LDS merge (no global atomics - R7).
// R15 fix vs R14: Z readback offset tile*256 uint4 (was tile*128 - read the
// wrong region for tile B -> absmax 1687).
// Structure: 1024 thr = 4 split-K groups x 4 waves; double-buffered staging;
// ONE barrier per k-iter; prefetch after the barrier; no-max exp2 softmax.
// ---------------------------------------------------------------------------
__global__ __launch_bounds__(1024, 4) void attn_kernel(
    const float* __restrict__ x,
    const float* __restrict__ Wk, const float* __restrict__ Wq,
    const float* __restrict__ Wv,
    float* __restrict__ out)
{
    __shared__ uint4 sStage[4096];  // 64 KB: group g at g*1024; buf d at +d*512:
                                    //  x_k bf16 [0..255] ([key][c], swz 16B)
                                    //  x^T f16 [256..511] ([c][key], swz 8B)
    __shared__ uint4 sP[512];       // 8 KB: Y (2 tiles) transient / l-merge
    __shared__ uint4 sG[128];       // 2 KB: G^T [c'][c] bf16, persistent

    int b  = blockIdx.x & 7;
    int pr = blockIdx.x >> 3;            // 0..31
    const int qtA = 63 - pr, qtB = pr;
    const int q0A = qtA * 64, q0B = qtB * 64;
    int tid  = threadIdx.x;
    int wave = tid >> 6, lane = tid & 63;
    int group = wave >> 2, gw = wave & 3;
    int ln15 = lane & 15, quad = lane >> 4;
    size_t bT = (size_t)b * Tt;

    // staging role: group's 256 threads cover the 64x32 slab, 8 c each
    const int tg = tid & 255;
    const int srow = tg >> 2, scg = tg & 3;

    // ---- G = (log2e Wq)·Wk^T [32x32], wave 0 computes -> sG (persistent) ----
    if (wave == 0) {
        floatx4 gC[2][2];
        #pragma unroll
        for (int mt = 0; mt < 2; ++mt)
            #pragma unroll
            for (int nt = 0; nt < 2; ++nt) gC[mt][nt] = (floatx4){0.f,0.f,0.f,0.f};
        #pragma unroll
        for (int kt = 0; kt < 2; ++kt) {
            short8 aG[2], bG[2];
            #pragma unroll
            for (int mt = 0; mt < 2; ++mt) {
                const float* qp = Wq + (ln15 + 16*mt)*64 + 32*kt + quad*8;
                float4 a = ((const float4_a*)qp)[0], bb = ((const float4_a*)qp)[1];
                a.x*=LOG2E; a.y*=LOG2E; a.z*=LOG2E; a.w*=LOG2E;
                bb.x*=LOG2E; bb.y*=LOG2E; bb.z*=LOG2E; bb.w*=LOG2E;
                aG[mt] = cvt8(a, bb);
                const float* kp = Wk + (ln15 + 16*mt)*64 + 32*kt + quad*8;
                bG[mt] = cvt8(((const float4_a*)kp)[0], ((const float4_a*)kp)[1]);
            }
            #pragma unroll
            for (int mt = 0; mt < 2; ++mt)
                #pragma unroll
                for (int nt = 0; nt < 2; ++nt)
                    gC[mt][nt] = MFMA16(aG[mt], bG[nt], gC[mt][nt]);
        }
        unsigned short* sGh = (unsigned short*)sG;
        #pragma unroll
        for (int mt = 0; mt < 2; ++mt)
            #pragma unroll
            for (int nt = 0; nt < 2; ++nt)
                *(ushort4_a*)(sGh + (16*nt + ln15)*32 + 16*mt + quad*4)
                    = pack4(gC[mt][nt]);
    }
    __syncthreads();

    const int gBase = group * 1024;      // group's 16 KB region (uint4 units)
    unsigned short* sYh = (unsigned short*)sP;

    // ---- prologue x-slab prefetch (kt = group): coalesced 32 B/thread ----
    float4 pX0, pX1;
    {
        const float* xp = x + (bT + group*64 + srow)*32 + scg*8;   // group<=qtA always
        pX0 = ((const float4_a*)xp)[0];
        pX1 = ((const float4_a*)xp)[1];
    }

    // ---- Y = x·G for BOTH tiles: wave w -> (tile w>>3, qs (w>>1)&3, mt w&1) ----
    {
        int tileY = wave >> 3, qs = (wave >> 1) & 3, mt = wave & 1;
        int q0Y = tileY ? q0B : q0A;
        union { uint4 u; short8 s; } g;
        g.u = sG[(16*mt + ln15)*4 + quad];
        const float* xp = x + (bT + q0Y + qs*16 + ln15)*32 + quad*8;
        short8 xq = cvt8(((const float4_a*)xp)[0], ((const float4_a*)xp)[1]);
        floatx4 d = (floatx4){0.f,0.f,0.f,0.f};
        d = MFMA16(g.s, xq, d);          // col=q=ln15, row=yc=16mt+quad*4+r
        *(ushort4_a*)(sYh + tileY*2048 + (qs*16 + ln15)*32 + 16*mt + quad*4)
            = pack4(d);
    }
    __syncthreads();
    short8 bqA, bqB;   // Y B-frags (n=q=ln15, k=yc=quad*8+j), K=32
    {
        union { uint4 u; short8 s; } t0, t1;
        t0.u = sP[(gw*16 + ln15)*4 + quad];
        t1.u = sP[256 + (gw*16 + ln15)*4 + quad];
        bqA = t0.s; bqB = t1.s;
    }

    floatx4 z4A[2], z4B[2];   // Z^T acc per tile (col=q=ln15, row=c')
    z4A[0] = (floatx4){0.f,0.f,0.f,0.f}; z4A[1] = z4A[0];
    z4B[0] = z4A[0];                     z4B[1] = z4A[0];
    float lA = 0.f, lB = 0.f;
    const int qrowA = q0A + gw*16 + ln15;
    const int qrowB = q0B + gw*16 + ln15;

    const int nIter = (qtA + 4) >> 2;

    for (int it = 0; it < nIter; ++it) {
        int kt = 4*it + group;
        bool activeA = (kt <= qtA);
        const int stB = gBase + (it & 1) * 512;   // double buffer
        if (activeA) {   // stage both layouts from the one coalesced load
            // x_k bf16 [key][c]: granule scg at scg^(srow&3)
            unsigned u0 = pk_bf2(pX0.x, pX0.y), u1 = pk_bf2(pX0.z, pX0.w);
            unsigned u2 = pk_bf2(pX1.x, pX1.y), u3 = pk_bf2(pX1.z, pX1.w);
            uint4 xu; xu.x = u0; xu.y = u1; xu.z = u2; xu.w = u3;
            sStage[stB + srow*4 + (scg ^ (srow & 3))] = xu;
            // x^T f16 [c][key]: rows 128 B, 8B-granule swizzle g^(c&15)
            union { half2v h; unsigned short us[2]; } w01, w23, w45, w67;
            w01.h = __builtin_amdgcn_cvt_pkrtz(pX0.x, pX0.y);
            w23.h = __builtin_amdgcn_cvt_pkrtz(pX0.z, pX0.w);
            w45.h = __builtin_amdgcn_cvt_pkrtz(pX1.x, pX1.y);
            w67.h = __builtin_amdgcn_cvt_pkrtz(pX1.z, pX1.w);
            unsigned short hv[8] = { w01.us[0], w01.us[1], w23.us[0], w23.us[1],
                                     w45.us[0], w45.us[1], w67.us[0], w67.us[1] };
            unsigned short* sXh = (unsigned short*)(sStage + stB + 256);
            const int cb = scg * 8, gx = srow >> 2, ko = srow & 3;
            #pragma unroll
            for (int jj = 0; jj < 8; ++jj) {
                int c = cb + jj;
                sXh[c*64 + ((gx ^ (c & 15)) << 2) + ko] = hv[jj];
            }
        }
        __syncthreads();             // single barrier: stage(it) visible;
                                     // buf reused at it+2, after barrier it+1
        int ktn = kt + 4;            // prefetch AFTER barrier -> in flight
        if (ktn <= qtA) {            // across all of compute
            const float* xp = x + (bT + ktn*64 + srow)*32 + scg*8;
            pX0 = ((const float4_a*)xp)[0];
            pX1 = ((const float4_a*)xp)[1];
        }
        if (!activeA) continue;
        int k0 = kt * 64;
        bool doB = (kt <= qtB);      // wave-uniform

        // ---- S^T = x_k · Y^T for A (and B): shared A-frag reads ----
        const int xsw = quad ^ (ln15 & 3);
        floatx4 sA[4], sB[4];
        #pragma unroll
        for (int t = 0; t < 4; ++t) {
            union { uint4 u; short8 s; } a;
            a.u = sStage[stB + (16*t + ln15)*4 + xsw];
            floatx4 c = (floatx4){0.f,0.f,0.f,0.f};
            sA[t] = MFMA16(a.s, bqA, c);
            if (doB) sB[t] = MFMA16(a.s, bqB, c);
        }

        // ---- p = exp2(s) in-register; mask only on each tile's diag ----
        if (kt == qtA) {
            #pragma unroll
            for (int t = 0; t < 4; ++t) {
                int keyb = k0 + 16*t + quad*4;
                #pragma unroll
                for (int r = 0; r < 4; ++r) {
                    float p = (keyb + r <= qrowA) ? __builtin_amdgcn_exp2f(sA[t][r]) : 0.f;
                    sA[t][r] = p; lA += p;
                }
            }
        } else {
            #pragma unroll
            for (int t = 0; t < 4; ++t)
                #pragma unroll
                for (int r = 0; r < 4; ++r) {
                    float p = __builtin_amdgcn_exp2f(sA[t][r]);
                    sA[t][r] = p; lA += p;
                }
        }
        if (doB) {
            if (kt == qtB) {
                #pragma unroll
                for (int t = 0; t < 4; ++t) {
                    int keyb = k0 + 16*t + quad*4;
                    #pragma unroll
                    for (int r = 0; r < 4; ++r) {
                        float p = (keyb + r <= qrowB) ? __builtin_amdgcn_exp2f(sB[t][r]) : 0.f;
                        sB[t][r] = p; lB += p;
                    }
                }
            } else {
                #pragma unroll
                for (int t = 0; t < 4; ++t)
                    #pragma unroll
                    for (int r = 0; r < 4; ++r) {
                        float p = __builtin_amdgcn_exp2f(sB[t][r]);
                        sB[t][r] = p; lB += p;
                    }
            }
        }

        // ---- Z^T += x^T · P^T : shared xa reads, P from registers ----
        const unsigned short* sXh = (const unsigned short*)(sStage + stB + 256);
        #pragma unroll
        for (int t = 0; t < 4; ++t) {
            union { half2v h2[2]; half4 h4; } pA, pB;
            pA.h2[0] = __builtin_amdgcn_cvt_pkrtz(sA[t][0], sA[t][1]);
            pA.h2[1] = __builtin_amdgcn_cvt_pkrtz(sA[t][2], sA[t][3]);
            if (doB) {
                pB.h2[0] = __builtin_amdgcn_cvt_pkrtz(sB[t][0], sB[t][1]);
                pB.h2[1] = __builtin_amdgcn_cvt_pkrtz(sB[t][2], sB[t][3]);
            }
            const int gph = ((4*t + quad) ^ ln15) << 2;
            #pragma unroll
            for (int mt = 0; mt < 2; ++mt) {
                half4 xa = *(const half4_a*)(sXh + (16*mt + ln15)*64 + gph);
                z4A[mt] = MFMAH16(xa, pA.h4, z4A[mt]);
                if (doB) z4B[mt] = MFMAH16(xa, pB.h4, z4B[mt]);
            }
        }
    }

    // ---- merge 4 groups' (Z^T, l) additively in LDS; group 0 finishes ----
    __syncthreads();                 // compute done; staging & sP free
    int li = gw*64 + lane;
    ((float*)sP)[wave*64 + lane] = lA;          // tile A l: floats [0..1023]
    ((float*)sP)[1024 + wave*64 + lane] = lB;   // tile B l: floats [1024..2047]
    if (group != 0) {
        float4* st = (float4*)(sStage + group*1024);
        st[li*2 + 0] = make_float4(z4A[0][0], z4A[0][1], z4A[0][2], z4A[0][3]);
        st[li*2 + 1] = make_float4(z4A[1][0], z4A[1][1], z4A[1][2], z4A[1][3]);
        st[512 + li*2 + 0] = make_float4(z4B[0][0], z4B[0][1], z4B[0][2], z4B[0][3]);
        st[512 + li*2 + 1] = make_float4(z4B[1][0], z4B[1][1], z4B[1][2], z4B[1][3]);
    }
    __syncthreads();
    if (group == 0) {
        // Wv^T A-frags loaded HERE (L2-hot), not loop-live
        short8 wv_f[4];
        #pragma unroll
        for (int t = 0; t < 4; ++t) {
            int col = 16*t + ln15;
            union { unsigned u[4]; short8 s; } rv;
            #pragma unroll
            for (int jj = 0; jj < 4; ++jj) {
                const float* v0 = Wv + (quad*8 + 2*jj) * 64 + col;
                rv.u[jj] = pk_bf2(v0[0], v0[64]);
            }
            wv_f[t] = rv.s;
        }
        unsigned short* sZb = (unsigned short*)sStage;
        #pragma unroll
        for (int tile = 0; tile < 2; ++tile) {
            floatx4* z4 = tile ? z4B : z4A;
            int lofs = tile * 1024, sofs = tile * 512;
            float l = ((float*)sP)[lofs + li] + ((float*)sP)[lofs + 256 + li]
                    + ((float*)sP)[lofs + 512 + li] + ((float*)sP)[lofs + 768 + li];
            l += __shfl_xor(l, 16);      // quads hold disjoint key subsets
            l += __shfl_xor(l, 32);
            float inv = 1.f / l;
            #pragma unroll
            for (int g = 1; g < 4; ++g) {
                float4* st = (float4*)(sStage + g*1024);
                float4 a = st[sofs + li*2 + 0], bb = st[sofs + li*2 + 1];
                z4[0][0]+=a.x; z4[0][1]+=a.y; z4[0][2]+=a.z; z4[0][3]+=a.w;
                z4[1][0]+=bb.x; z4[1][1]+=bb.y; z4[1][2]+=bb.z; z4[1][3]+=bb.w;
            }
            // pack merged Z as bf16 [q][c] into group-0 staging; same-wave readback
            #pragma unroll
            for (int mt = 0; mt < 2; ++mt)
                *(ushort4_a*)(sZb + tile*2048 + (gw*16 + ln15)*32 + 16*mt + quad*4)
                    = pack4(z4[mt]);
            union { uint4 u; short8 s; } zb;
            zb.u = sStage[tile*256 + (gw*16 + ln15)*4 + quad];   // R15 FIX: tile*256
            // O^T = Wv^T · Z^T : 4 MFMA (K=32); col=q=ln15, row=d=16t+quad*4+r
            int q0T = tile ? q0B : q0A;
            #pragma unroll
            for (int t = 0; t < 4; ++t) {
                floatx4 o = (floatx4){0.f,0.f,0.f,0.f};
                o = MFMA16(wv_f[t], zb.s, o);
                *(float4_a*)(out + (bT + q0T + gw*16 + ln15)*Dd + 16*t + quad*4)
                    = make_float4(o[0]*inv, o[1]*inv, o[2]*inv, o[3]*inv);
            }
        }
    }
}

// ---------------------------------------------------------------------------
extern "C" void kernel_launch(void* const* d_in, const int* in_sizes, int n_in,
                              void* d_out, int out_size, void* d_ws, size_t ws_size,
                              hipStream_t stream)
{
    const float* x  = (const float*)d_in[0];
    const float* Wk = (const float*)d_in[1];   // setup_inputs order: x, Wk, Wq, Wv
    const float* Wq = (const float*)d_in[2];
    const float* Wv = (const float*)d_in[3];
    float* out = (float*)d_out;

    // 256 blocks (one per CU), 1024 threads, 74 KB LDS, <=16 shared k-iters
    attn_kernel<<<Bc * 32, 1024, 0, stream>>>(x, Wk, Wq, Wv, out);
}

// Round 16
// 89.469 us; speedup vs baseline: 1.0126x; 1.0126x over previous
//
#include <hip/hip_runtime.h>
#include <hip/hip_bf16.h>

// B=8, T=4096, C=32, D=64. Causal, no 1/sqrt(D) scaling.
constexpr int Bc = 8;
constexpr int Tt = 4096;
constexpr int Dd = 64;

typedef __attribute__((ext_vector_type(8))) short short8;   // 8 bf16 = 4 VGPRs
typedef __attribute__((ext_vector_type(4))) float floatx4;  // MFMA C/D frag
typedef __attribute__((ext_vector_type(4))) __fp16 half4;   // 4 f16 = 2 VGPRs
typedef __attribute__((ext_vector_type(2))) __fp16 half2v;
typedef uint4   __attribute__((may_alias)) uint4_a;
typedef short8  __attribute__((may_alias)) short8_a;
typedef ushort4 __attribute__((may_alias)) ushort4_a;
typedef float4  __attribute__((may_alias)) float4_a;
typedef half4   __attribute__((may_alias)) half4_a;

#define MFMA16(A, B, C)  __builtin_amdgcn_mfma_f32_16x16x32_bf16(A, B, C, 0, 0, 0)
#define MFMAH16(A, B, C) __builtin_amdgcn_mfma_f32_16x16x16f16(A, B, C, 0, 0, 0)
constexpr float LOG2E = 1.4426950408889634f;

// ---- fast fp32 -> bf16: round-half-up (u + 0x8000), pack 2 via v_perm ----
__device__ __forceinline__ unsigned rnd16(float x) {
    unsigned u; __builtin_memcpy(&u, &x, 4); return u + 0x8000u;
}
__device__ __forceinline__ unsigned pk_bf2(float lo, float hi) {
    return __builtin_amdgcn_perm(rnd16(hi), rnd16(lo), 0x07060302);
}
__device__ __forceinline__ ushort4 pack4(floatx4 d) {
    union { unsigned u[2]; ushort4 v; } r;
    r.u[0] = pk_bf2(d[0], d[1]);
    r.u[1] = pk_bf2(d[2], d[3]);
    return r.v;
}
__device__ __forceinline__ short8 cvt8(float4 a, float4 b) {
    union { unsigned u[4]; short8 s; } r;
    r.u[0] = pk_bf2(a.x, a.y);
    r.u[1] = pk_bf2(a.z, a.w);
    r.u[2] = pk_bf2(b.x, b.y);
    r.u[3] = pk_bf2(b.z, b.w);
    return r.s;
}

// ---------------------------------------------------------------------------
// Associativity-refactored fused attention (R9 algebra) with a SINGLE shared
// k-loop for the balanced q-tile pair (R14/R15) and a small live set (R16):
//   Block pr owns q-tiles A = 63-pr and B = pr; ONE k-loop serves both (B's
//   k-range is a prefix of A's): staged x-slab, S^T A-frag b128 reads and
//   Z^T xa b64 reads are SHARED between the two q-tiles.
//   G = (log2e Wq)Wk^T [32x32] once; Y = x·G for both tiles upfront;
//   S^T = x_k·Y^T (K=32 bf16); P feeds PV directly from registers via
//   mfma_16x16x16_f16 (B-operand layout == C/D layout); Z^T += x^T·P^T;
//   O^T = Wv^T·Z^T after the additive LDS merge (no global atomics - R7).
// R16 vs R15: per-t subtile computes S -> exp -> pack to half4 pA[t]/pB[t]
// IMMEDIATELY (2 regs each), so the 32-reg sA[]/sB[] arrays never exist ->
// peak live ~80 VGPRs, no spill risk (R15's suspected regression cause).
// Structure: 1024 thr = 4 split-K groups x 4 waves; double-buffered staging;
// ONE barrier per k-iter; prefetch after the barrier; no-max exp2 softmax.
// ---------------------------------------------------------------------------
__global__ __launch_bounds__(1024, 4) void attn_kernel(
    const float* __restrict__ x,
    const float* __restrict__ Wk, const float* __restrict__ Wq,
    const float* __restrict__ Wv,
    float* __restrict__ out)
{
    __shared__ uint4 sStage[4096];  // 64 KB: group g at g*1024; buf d at +d*512:
                                    //  x_k bf16 [0..255] ([key][c], swz 16B)
                                    //  x^T f16 [256..511] ([c][key], swz 8B)
    __shared__ uint4 sP[512];       // 8 KB: Y (2 tiles) transient / l-merge
    __shared__ uint4 sG[128];       // 2 KB: G^T [c'][c] bf16, persistent

    int b  = blockIdx.x & 7;
    int pr = blockIdx.x >> 3;            // 0..31
    const int qtA = 63 - pr, qtB = pr;
    const int q0A = qtA * 64, q0B = qtB * 64;
    int tid  = threadIdx.x;
    int wave = tid >> 6, lane = tid & 63;
    int group = wave >> 2, gw = wave & 3;
    int ln15 = lane & 15, quad = lane >> 4;
    size_t bT = (size_t)b * Tt;

    // staging role: group's 256 threads cover the 64x32 slab, 8 c each
    const int tg = tid & 255;
    const int srow = tg >> 2, scg = tg & 3;

    // ---- G = (log2e Wq)·Wk^T [32x32], wave 0 computes -> sG (persistent) ----
    if (wave == 0) {
        floatx4 gC[2][2];
        #pragma unroll
        for (int mt = 0; mt < 2; ++mt)
            #pragma unroll
            for (int nt = 0; nt < 2; ++nt) gC[mt][nt] = (floatx4){0.f,0.f,0.f,0.f};
        #pragma unroll
        for (int kt = 0; kt < 2; ++kt) {
            short8 aG[2], bG[2];
            #pragma unroll
            for (int mt = 0; mt < 2; ++mt) {
                const float* qp = Wq + (ln15 + 16*mt)*64 + 32*kt + quad*8;
                float4 a = ((const float4_a*)qp)[0], bb = ((const float4_a*)qp)[1];
                a.x*=LOG2E; a.y*=LOG2E; a.z*=LOG2E; a.w*=LOG2E;
                bb.x*=LOG2E; bb.y*=LOG2E; bb.z*=LOG2E; bb.w*=LOG2E;
                aG[mt] = cvt8(a, bb);
                const float* kp = Wk + (ln15 + 16*mt)*64 + 32*kt + quad*8;
                bG[mt] = cvt8(((const float4_a*)kp)[0], ((const float4_a*)kp)[1]);
            }
            #pragma unroll
            for (int mt = 0; mt < 2; ++mt)
                #pragma unroll
                for (int nt = 0; nt < 2; ++nt)
                    gC[mt][nt] = MFMA16(aG[mt], bG[nt], gC[mt][nt]);
        }
        unsigned short* sGh = (unsigned short*)sG;
        #pragma unroll
        for (int mt = 0; mt < 2; ++mt)
            #pragma unroll
            for (int nt = 0; nt < 2; ++nt)
                *(ushort4_a*)(sGh + (16*nt + ln15)*32 + 16*mt + quad*4)
                    = pack4(gC[mt][nt]);
    }
    __syncthreads();

    const int gBase = group * 1024;      // group's 16 KB region (uint4 units)
    unsigned short* sYh = (unsigned short*)sP;

    // ---- prologue x-slab prefetch (kt = group): coalesced 32 B/thread ----
    float4 pX0, pX1;
    {
        const float* xp = x + (bT + group*64 + srow)*32 + scg*8;   // group<=qtA always
        pX0 = ((const float4_a*)xp)[0];
        pX1 = ((const float4_a*)xp)[1];
    }

    // ---- Y = x·G for BOTH tiles: wave w -> (tile w>>3, qs (w>>1)&3, mt w&1) ----
    {
        int tileY = wave >> 3, qs = (wave >> 1) & 3, mt = wave & 1;
        int q0Y = tileY ? q0B : q0A;
        union { uint4 u; short8 s; } g;
        g.u = sG[(16*mt + ln15)*4 + quad];
        const float* xp = x + (bT + q0Y + qs*16 + ln15)*32 + quad*8;
        short8 xq = cvt8(((const float4_a*)xp)[0], ((const float4_a*)xp)[1]);
        floatx4 d = (floatx4){0.f,0.f,0.f,0.f};
        d = MFMA16(g.s, xq, d);          // col=q=ln15, row=yc=16mt+quad*4+r
        *(ushort4_a*)(sYh + tileY*2048 + (qs*16 + ln15)*32 + 16*mt + quad*4)
            = pack4(d);
    }
    __syncthreads();
    short8 bqA, bqB;   // Y B-frags (n=q=ln15, k=yc=quad*8+j), K=32
    {
        union { uint4 u; short8 s; } t0, t1;
        t0.u = sP[(gw*16 + ln15)*4 + quad];
        t1.u = sP[256 + (gw*16 + ln15)*4 + quad];
        bqA = t0.s; bqB = t1.s;
    }

    floatx4 z4A[2], z4B[2];   // Z^T acc per tile (col=q=ln15, row=c')
    z4A[0] = (floatx4){0.f,0.f,0.f,0.f}; z4A[1] = z4A[0];
    z4B[0] = z4A[0];                     z4B[1] = z4A[0];
    float lA = 0.f, lB = 0.f;
    const int qrowA = q0A + gw*16 + ln15;
    const int qrowB = q0B + gw*16 + ln15;

    const int nIter = (qtA + 4) >> 2;

    for (int it = 0; it < nIter; ++it) {
        int kt = 4*it + group;
        bool activeA = (kt <= qtA);
        const int stB = gBase + (it & 1) * 512;   // double buffer
        if (activeA) {   // stage both layouts from the one coalesced load
            // x_k bf16 [key][c]: granule scg at scg^(srow&3)
            unsigned u0 = pk_bf2(pX0.x, pX0.y), u1 = pk_bf2(pX0.z, pX0.w);
            unsigned u2 = pk_bf2(pX1.x, pX1.y), u3 = pk_bf2(pX1.z, pX1.w);
            uint4 xu; xu.x = u0; xu.y = u1; xu.z = u2; xu.w = u3;
            sStage[stB + srow*4 + (scg ^ (srow & 3))] = xu;
            // x^T f16 [c][key]: rows 128 B, 8B-granule swizzle g^(c&15)
            union { half2v h; unsigned short us[2]; } w01, w23, w45, w67;
            w01.h = __builtin_amdgcn_cvt_pkrtz(pX0.x, pX0.y);
            w23.h = __builtin_amdgcn_cvt_pkrtz(pX0.z, pX0.w);
            w45.h = __builtin_amdgcn_cvt_pkrtz(pX1.x, pX1.y);
            w67.h = __builtin_amdgcn_cvt_pkrtz(pX1.z, pX1.w);
            unsigned short hv[8] = { w01.us[0], w01.us[1], w23.us[0], w23.us[1],
                                     w45.us[0], w45.us[1], w67.us[0], w67.us[1] };
            unsigned short* sXh = (unsigned short*)(sStage + stB + 256);
            const int cb = scg * 8, gx = srow >> 2, ko = srow & 3;
            #pragma unroll
            for (int jj = 0; jj < 8; ++jj) {
                int c = cb + jj;
                sXh[c*64 + ((gx ^ (c & 15)) << 2) + ko] = hv[jj];
            }
        }
        __syncthreads();             // single barrier: stage(it) visible;
                                     // buf reused at it+2, after barrier it+1
        int ktn = kt + 4;            // prefetch AFTER barrier -> in flight
        if (ktn <= qtA) {            // across all of compute
            const float* xp = x + (bT + ktn*64 + srow)*32 + scg*8;
            pX0 = ((const float4_a*)xp)[0];
            pX1 = ((const float4_a*)xp)[1];
        }
        if (!activeA) continue;
        int k0 = kt * 64;
        bool doB = (kt <= qtB);      // wave-uniform

        // ---- per-t: S^T MFMA -> exp -> pack to half4 immediately (R16) ----
        const int xsw = quad ^ (ln15 & 3);
        half4 pA[4], pB[4];
        const bool diagA = (kt == qtA), diagB = (kt == qtB);
        #pragma unroll
        for (int t = 0; t < 4; ++t) {
            union { uint4 u; short8 s; } a;
            a.u = sStage[stB + (16*t + ln15)*4 + xsw];   // shared A-frag read
            const int keyb = k0 + 16*t + quad*4;
            floatx4 cz = (floatx4){0.f,0.f,0.f,0.f};
            {
                floatx4 s = MFMA16(a.s, bqA, cz);
                float p0, p1, p2, p3;
                if (diagA) {
                    p0 = (keyb + 0 <= qrowA) ? __builtin_amdgcn_exp2f(s[0]) : 0.f;
                    p1 = (keyb + 1 <= qrowA) ? __builtin_amdgcn_exp2f(s[1]) : 0.f;
                    p2 = (keyb + 2 <= qrowA) ? __builtin_amdgcn_exp2f(s[2]) : 0.f;
                    p3 = (keyb + 3 <= qrowA) ? __builtin_amdgcn_exp2f(s[3]) : 0.f;
                } else {
                    p0 = __builtin_amdgcn_exp2f(s[0]);
                    p1 = __builtin_amdgcn_exp2f(s[1]);
                    p2 = __builtin_amdgcn_exp2f(s[2]);
                    p3 = __builtin_amdgcn_exp2f(s[3]);
                }
                lA += p0 + p1 + p2 + p3;
                union { half2v h2[2]; half4 h4; } u;
                u.h2[0] = __builtin_amdgcn_cvt_pkrtz(p0, p1);
                u.h2[1] = __builtin_amdgcn_cvt_pkrtz(p2, p3);
                pA[t] = u.h4;
            }
            if (doB) {
                floatx4 s = MFMA16(a.s, bqB, cz);
                float p0, p1, p2, p3;
                if (diagB) {
                    p0 = (keyb + 0 <= qrowB) ? __builtin_amdgcn_exp2f(s[0]) : 0.f;
                    p1 = (keyb + 1 <= qrowB) ? __builtin_amdgcn_exp2f(s[1]) : 0.f;
                    p2 = (keyb + 2 <= qrowB) ? __builtin_amdgcn_exp2f(s[2]) : 0.f;
                    p3 = (keyb + 3 <= qrowB) ? __builtin_amdgcn_exp2f(s[3]) : 0.f;
                } else {
                    p0 = __builtin_amdgcn_exp2f(s[0]);
                    p1 = __builtin_amdgcn_exp2f(s[1]);
                    p2 = __builtin_amdgcn_exp2f(s[2]);
                    p3 = __builtin_amdgcn_exp2f(s[3]);
                }
                lB += p0 + p1 + p2 + p3;
                union { half2v h2[2]; half4 h4; } u;
                u.h2[0] = __builtin_amdgcn_cvt_pkrtz(p0, p1);
                u.h2[1] = __builtin_amdgcn_cvt_pkrtz(p2, p3);
                pB[t] = u.h4;
            }
        }

        // ---- Z^T += x^T · P^T : shared xa reads, P from registers ----
        const unsigned short* sXh = (const unsigned short*)(sStage + stB + 256);
        #pragma unroll
        for (int t = 0; t < 4; ++t) {
            const int gph = ((4*t + quad) ^ ln15) << 2;
            #pragma unroll
            for (int mt = 0; mt < 2; ++mt) {
                half4 xa = *(const half4_a*)(sXh + (16*mt + ln15)*64 + gph);
                z4A[mt] = MFMAH16(xa, pA[t], z4A[mt]);
                if (doB) z4B[mt] = MFMAH16(xa, pB[t], z4B[mt]);
            }
        }
    }

    // ---- merge 4 groups' (Z^T, l) additively in LDS; group 0 finishes ----
    __syncthreads();                 // compute done; staging & sP free
    int li = gw*64 + lane;
    ((float*)sP)[wave*64 + lane] = lA;          // tile A l: floats [0..1023]
    ((float*)sP)[1024 + wave*64 + lane] = lB;   // tile B l: floats [1024..2047]
    if (group != 0) {
        float4* st = (float4*)(sStage + group*1024);
        st[li*2 + 0] = make_float4(z4A[0][0], z4A[0][1], z4A[0][2], z4A[0][3]);
        st[li*2 + 1] = make_float4(z4A[1][0], z4A[1][1], z4A[1][2], z4A[1][3]);
        st[512 + li*2 + 0] = make_float4(z4B[0][0], z4B[0][1], z4B[0][2], z4B[0][3]);
        st[512 + li*2 + 1] = make_float4(z4B[1][0], z4B[1][1], z4B[1][2], z4B[1][3]);
    }
    __syncthreads();
    if (group == 0) {
        // Wv^T A-frags loaded HERE (L2-hot), not loop-live
        short8 wv_f[4];
        #pragma unroll
        for (int t = 0; t < 4; ++t) {
            int col = 16*t + ln15;
            union { unsigned u[4]; short8 s; } rv;
            #pragma unroll
            for (int jj = 0; jj < 4; ++jj) {
                const float* v0 = Wv + (quad*8 + 2*jj) * 64 + col;
                rv.u[jj] = pk_bf2(v0[0], v0[64]);
            }
            wv_f[t] = rv.s;
        }
        unsigned short* sZb = (unsigned short*)sStage;
        #pragma unroll
        for (int tile = 0; tile < 2; ++tile) {
            floatx4* z4 = tile ? z4B : z4A;
            int lofs = tile * 1024, sofs = tile * 512;
            float l = ((float*)sP)[lofs + li] + ((float*)sP)[lofs + 256 + li]
                    + ((float*)sP)[lofs + 512 + li] + ((float*)sP)[lofs + 768 + li];
            l += __shfl_xor(l, 16);      // quads hold disjoint key subsets
            l += __shfl_xor(l, 32);
            float inv = 1.f / l;
            #pragma unroll
            for (int g = 1; g < 4; ++g) {
                float4* st = (float4*)(sStage + g*1024);
                float4 a = st[sofs + li*2 + 0], bb = st[sofs + li*2 + 1];
                z4[0][0]+=a.x; z4[0][1]+=a.y; z4[0][2]+=a.z; z4[0][3]+=a.w;
                z4[1][0]+=bb.x; z4[1][1]+=bb.y; z4[1][2]+=bb.z; z4[1][3]+=bb.w;
            }
            // pack merged Z as bf16 [q][c] into group-0 staging; same-wave readback
            #pragma unroll
            for (int mt = 0; mt < 2; ++mt)
                *(ushort4_a*)(sZb + tile*2048 + (gw*16 + ln15)*32 + 16*mt + quad*4)
                    = pack4(z4[mt]);
            union { uint4 u; short8 s; } zb;
            zb.u = sStage[tile*256 + (gw*16 + ln15)*4 + quad];
            // O^T = Wv^T · Z^T : 4 MFMA (K=32); col=q=ln15, row=d=16t+quad*4+r
            int q0T = tile ? q0B : q0A;
            #pragma unroll
            for (int t = 0; t < 4; ++t) {
                floatx4 o = (floatx4){0.f,0.f,0.f,0.f};
                o = MFMA16(wv_f[t], zb.s, o);
                *(float4_a*)(out + (bT + q0T + gw*16 + ln15)*Dd + 16*t + quad*4)
                    = make_float4(o[0]*inv, o[1]*inv, o[2]*inv, o[3]*inv);
            }
        }
    }
}

// ---------------------------------------------------------------------------
extern "C" void kernel_launch(void* const* d_in, const int* in_sizes, int n_in,
                              void* d_out, int out_size, void* d_ws, size_t ws_size,
                              hipStream_t stream)
{
    const float* x  = (const float*)d_in[0];
    const float* Wk = (const float*)d_in[1];   // setup_inputs order: x, Wk, Wq, Wv
    const float* Wq = (const float*)d_in[2];
    const float* Wv = (const float*)d_in[3];
    float* out = (float*)d_out;

    // 256 blocks (one per CU), 1024 threads, 74 KB LDS, <=16 shared k-iters
    attn_kernel<<<Bc * 32, 1024, 0, stream>>>(x, Wk, Wq, Wv, out);
}